// Round 7
// baseline (7632.716 us; speedup 1.0000x reference)
//
#include <hip/hip_runtime.h>
#include <hip/hip_bf16.h>

#define NN 100000
#define NE 1600000
#define NCHUNK 391   // ceil(100000/256)

typedef unsigned short u16;
typedef unsigned int   u32;

__device__ __forceinline__ float bfu(u32 v){ union{u32 i; float f;} w; w.i = v<<16; return w.f; }
__device__ __forceinline__ float bf_lo(u32 u){ return bfu(u & 0xffffu); }
__device__ __forceinline__ float bf_hi(u32 u){ return bfu(u >> 16); }
__device__ __forceinline__ float bf16f(u16 u){ return bfu((u32)u); }
__device__ __forceinline__ u16 f2bf(float f){
    union{float f; u32 i;} w; w.f = f;
    u32 r = (w.i + 0x7fffu + ((w.i >> 16) & 1u)) >> 16;   // RNE
    return (u16)r;
}

template<int IS32>
__device__ __forceinline__ float ldx(const void* p, int i){
    if (IS32) return ((const float*)p)[i];
    else      return bf16f(((const u16*)p)[i]);
}

// ---------------- dtype sniff: fp32 (1) vs bf16 (0) ----------------
__global__ void k_sniff(const u32* __restrict__ x, int* __restrict__ flag){
    __shared__ int cnt[256];
    int t = threadIdx.x;
    int bad = 0;
    for (int i = t; i < 512; i += 256){
        u32 w = x[i];
        u32 lo = w & 0xffffu;
        u32 e = (lo >> 7) & 0xffu;
        bool sane = (lo == 0u) || (lo == 0x8000u) || (e >= 85u && e <= 133u);
        if (!sane) bad++;
    }
    cnt[t] = bad; __syncthreads();
    for (int s = 128; s > 0; s >>= 1){
        if (t < s) cnt[t] += cnt[t+s];
        __syncthreads();
    }
    if (t == 0) flag[0] = (cnt[0] > 100) ? 1 : 0;
}

// ---------------- CSR build ----------------

__global__ void k_deg(const int* __restrict__ dst, int* __restrict__ deg){
    int stride = gridDim.x * blockDim.x;
    for (int i = blockIdx.x*blockDim.x + threadIdx.x; i < NE; i += stride){
        int d = dst[i];
        if ((unsigned)d < (unsigned)NN) atomicAdd(&deg[d], 1);
    }
}

__global__ void k_csum(const int* __restrict__ deg, int* __restrict__ csum){
    __shared__ int sdata[256];
    int t = threadIdx.x;
    int idx = blockIdx.x*256 + t;
    sdata[t] = (idx < NN) ? deg[idx] : 0;
    __syncthreads();
    for (int s = 128; s > 0; s >>= 1){
        if (t < s) sdata[t] += sdata[t+s];
        __syncthreads();
    }
    if (t == 0) csum[blockIdx.x] = sdata[0];
}

__global__ void k_scan_chunks(const int* __restrict__ csum, int* __restrict__ coff){
    __shared__ int s[512];
    int t = threadIdx.x;
    int v = (t < NCHUNK) ? csum[t] : 0;
    s[t] = v; __syncthreads();
    int x = v;
    for (int off = 1; off < 512; off <<= 1){
        int y = (t >= off) ? s[t-off] : 0;
        __syncthreads();
        x += y; s[t] = x;
        __syncthreads();
    }
    if (t < NCHUNK) coff[t] = x - v;   // exclusive
}

__global__ void k_rowptr(const int* __restrict__ deg, const int* __restrict__ coff,
                         int* __restrict__ row_ptr){
    __shared__ int s[256];
    int t = threadIdx.x, b = blockIdx.x;
    int idx = b*256 + t;
    int v = (idx < NN) ? deg[idx] : 0;
    s[t] = v; __syncthreads();
    int x = v;
    for (int off = 1; off < 256; off <<= 1){
        int y = (t >= off) ? s[t-off] : 0;
        __syncthreads();
        x += y; s[t] = x;
        __syncthreads();
    }
    if (idx < NN)       row_ptr[idx] = coff[b] + x - v;   // exclusive
    if (idx == NN - 1)  row_ptr[NN]  = coff[b] + x;       // total = NE
}

// sorted mode: also transpose edge_attr into CSR order (bf16)
template<int IS32>
__global__ void k_scatter_s(const int* __restrict__ src, const int* __restrict__ dst,
                            const void* __restrict__ ea,
                            const int* __restrict__ row_ptr, int* __restrict__ fill,
                            const int* __restrict__ flg,
                            int* __restrict__ src_sorted, u16* __restrict__ ea_sorted){
    if (flg[0] != IS32) return;
    int stride = gridDim.x * blockDim.x;
    for (int i = blockIdx.x*blockDim.x + threadIdx.x; i < NE; i += stride){
        int d = dst[i];
        if ((unsigned)d >= (unsigned)NN) continue;
        int p = row_ptr[d] + atomicAdd(&fill[d], 1);
        if ((unsigned)p >= (unsigned)NE) continue;
        int s = src[i];
        if ((unsigned)s >= (unsigned)NN) s = 0;
        src_sorted[p] = s;
        u16* o = ea_sorted + (size_t)p*16;
        #pragma unroll
        for (int k = 0; k < 16; k++){
            float v = ldx<IS32>(ea, i*16 + k);
            o[k] = f2bf(v);
        }
    }
}

// fallback mode: (src, edge_id) pairs only
__global__ void k_scatter_f(const int* __restrict__ src, const int* __restrict__ dst,
                            const int* __restrict__ row_ptr, int* __restrict__ fill,
                            int2* __restrict__ pair_sorted){
    int stride = gridDim.x * blockDim.x;
    for (int i = blockIdx.x*blockDim.x + threadIdx.x; i < NE; i += stride){
        int d = dst[i];
        if ((unsigned)d >= (unsigned)NN) continue;
        int p = row_ptr[d] + atomicAdd(&fill[d], 1);
        if ((unsigned)p < (unsigned)NE){
            int s = src[i];
            if ((unsigned)s >= (unsigned)NN) s = 0;
            pair_sorted[p] = make_int2(s, i);
        }
    }
}

// ---------------- input projection: h = x @ src_w + src_b (bf16 out) ----------------
template<int IS32>
__global__ __launch_bounds__(256) void k_proj(const void* __restrict__ x,
                                              const void* __restrict__ w,
                                              const void* __restrict__ b,
                                              const int* __restrict__ flg,
                                              u16* __restrict__ h){
    if (flg[0] != IS32) return;
    int lane = threadIdx.x & 63;
    int wid  = (blockIdx.x*256 + threadIdx.x) >> 6;
    int nw   = (gridDim.x*256) >> 6;
    float wr[32];
    #pragma unroll
    for (int k = 0; k < 32; k++) wr[k] = ldx<IS32>(w, k*64 + lane);
    float bias = ldx<IS32>(b, lane);
    for (int node = wid; node < NN; node += nw){
        float acc = bias;
        #pragma unroll
        for (int k = 0; k < 32; k++) acc = fmaf(ldx<IS32>(x, node*32 + k), wr[k], acc);
        h[(size_t)node*64 + lane] = f2bf(acc);
    }
}

__device__ __forceinline__ float dot16bf(uint4 a0, uint4 a1, const float* ewr, float e){
    e = fmaf(bf_lo(a0.x), ewr[0],  e); e = fmaf(bf_hi(a0.x), ewr[1],  e);
    e = fmaf(bf_lo(a0.y), ewr[2],  e); e = fmaf(bf_hi(a0.y), ewr[3],  e);
    e = fmaf(bf_lo(a0.z), ewr[4],  e); e = fmaf(bf_hi(a0.z), ewr[5],  e);
    e = fmaf(bf_lo(a0.w), ewr[6],  e); e = fmaf(bf_hi(a0.w), ewr[7],  e);
    e = fmaf(bf_lo(a1.x), ewr[8],  e); e = fmaf(bf_hi(a1.x), ewr[9],  e);
    e = fmaf(bf_lo(a1.y), ewr[10], e); e = fmaf(bf_hi(a1.y), ewr[11], e);
    e = fmaf(bf_lo(a1.z), ewr[12], e); e = fmaf(bf_hi(a1.z), ewr[13], e);
    e = fmaf(bf_lo(a1.w), ewr[14], e); e = fmaf(bf_hi(a1.w), ewr[15], e);
    return e;
}

// ---------------- fused GENConv layer ----------------
// SORTED=1: stream ea_sorted bf16 + src_sorted (unroll x2, no-shift softmax)
// SORTED=0: gather original ea via (src, eid) pairs (R6 fallback)
template<int IS32, int SORTED>
__global__ __launch_bounds__(256, 4) void k_layer(
    const u16*   __restrict__ h_in,
    const int*   __restrict__ row_ptr,
    const int*   __restrict__ src_sorted,
    const uint4* __restrict__ eas4,        // ea_sorted viewed as uint4[NE*2]
    const int2*  __restrict__ pair_sorted,
    const void*  __restrict__ ea,
    const void* __restrict__ ew, const void* __restrict__ eb,
    const void* __restrict__ w1, const void* __restrict__ b1,
    const void* __restrict__ g,  const void* __restrict__ bb,
    const void* __restrict__ w2, const void* __restrict__ b2,
    const int* __restrict__ flg,
    u16* __restrict__ h_out)
{
    if (flg[0] != IS32) return;

    __shared__ u32 w1p[64*64];   // lo=w1[k][c], hi=w1[k][c+64]  (bf16 pair)
    __shared__ u32 w2p[64*64];   // lo=w2[j][c], hi=w2[j+64][c]  (bf16 pair)

    int t = threadIdx.x;
    for (int i = t; i < 64*64; i += 256){
        int k = i >> 6, c = i & 63;
        u32 lo, hi;
        if (IS32){
            lo = f2bf(((const float*)w1)[k*128 + c]);
            hi = f2bf(((const float*)w1)[k*128 + c + 64]);
        } else {
            lo = ((const u16*)w1)[k*128 + c];
            hi = ((const u16*)w1)[k*128 + c + 64];
        }
        w1p[i] = lo | (hi << 16);
        if (IS32){
            lo = f2bf(((const float*)w2)[k*64 + c]);
            hi = f2bf(((const float*)w2)[(k+64)*64 + c]);
        } else {
            lo = ((const u16*)w2)[k*64 + c];
            hi = ((const u16*)w2)[(k+64)*64 + c];
        }
        w2p[i] = lo | (hi << 16);
    }
    __syncthreads();

    int lane = t & 63;
    int wid  = (blockIdx.x*256 + t) >> 6;
    int nw   = (gridDim.x*256) >> 6;

    float ewr[16];
    #pragma unroll
    for (int k = 0; k < 16; k++) ewr[k] = ldx<IS32>(ew, k*64 + lane);
    float ebr = ldx<IS32>(eb, lane);
    const float BNS = 0.9999950000374997f;   // 1/sqrt(1+1e-5)
    float b1a = ldx<IS32>(b1, lane), b1b = ldx<IS32>(b1, lane+64);
    float ga  = ldx<IS32>(g, lane)*BNS,  gb  = ldx<IS32>(g, lane+64)*BNS;
    float bba = ldx<IS32>(bb, lane),     bbb = ldx<IS32>(bb, lane+64);
    float b2r = ldx<IS32>(b2, lane);

    for (int node = wid; node < NN; node += nw){
        int p0 = row_ptr[node], p1 = row_ptr[node+1];
        float swA = 0.f, swB = 0.f, smA = 0.f, smB = 0.f;
        int p = p0;
        if (SORTED){
            for (; p + 2 <= p1; p += 2){
                int s0 = src_sorted[p];
                int s1 = src_sorted[p+1];
                uint4 a0 = eas4[(size_t)p*2+0], a1 = eas4[(size_t)p*2+1];
                uint4 b0 = eas4[(size_t)p*2+2], b1 = eas4[(size_t)p*2+3];
                float h0 = bf16f(h_in[(size_t)s0*64 + lane]);
                float h1 = bf16f(h_in[(size_t)s1*64 + lane]);
                float e0 = dot16bf(a0, a1, ewr, ebr);
                float e1 = dot16bf(b0, b1, ewr, ebr);
                float v0 = fmaxf(h0 + e0, 0.f) + 1e-7f;
                float v1 = fmaxf(h1 + e1, 0.f) + 1e-7f;
                float x0 = __expf(v0), x1 = __expf(v1);
                swA += x0; smA = fmaf(x0, v0, smA);
                swB += x1; smB = fmaf(x1, v1, smB);
            }
            for (; p < p1; ++p){
                int s0 = src_sorted[p];
                uint4 a0 = eas4[(size_t)p*2+0], a1 = eas4[(size_t)p*2+1];
                float h0 = bf16f(h_in[(size_t)s0*64 + lane]);
                float v0 = fmaxf(h0 + dot16bf(a0, a1, ewr, ebr), 0.f) + 1e-7f;
                float x0 = __expf(v0);
                swA += x0; smA = fmaf(x0, v0, smA);
            }
        } else {
            for (; p < p1; ++p){
                int2 pe = pair_sorted[p];
                int s0 = pe.x;
                unsigned eid = (unsigned)pe.y;
                if (eid >= (unsigned)NE) eid = 0;
                float e0 = ebr;
                #pragma unroll
                for (int k = 0; k < 16; k++) e0 = fmaf(ldx<IS32>(ea, (int)eid*16 + k), ewr[k], e0);
                float h0 = bf16f(h_in[(size_t)s0*64 + lane]);
                float v0 = fmaxf(h0 + e0, 0.f) + 1e-7f;
                float x0 = __expf(v0);
                swA += x0; smA = fmaf(x0, v0, smA);
            }
        }
        float sw = swA + swB, swm = smA + smB;
        float agg = (sw > 0.f) ? (swm / sw) : 0.f;
        float out = agg + bf16f(h_in[(size_t)node*64 + lane]);

        // MLP: 64 -> 128 (BN + relu) -> 64, then outer relu
        float acc1 = b1a, acc2 = b1b;
        #pragma unroll
        for (int k = 0; k < 64; k++){
            float ok = __shfl(out, k, 64);
            u32 wp = w1p[k*64 + lane];
            acc1 = fmaf(ok, bf_lo(wp), acc1);
            acc2 = fmaf(ok, bf_hi(wp), acc2);
        }
        float hh1 = fmaxf(fmaf(acc1, ga, bba), 0.f);
        float hh2 = fmaxf(fmaf(acc2, gb, bbb), 0.f);
        float acc = b2r;
        #pragma unroll
        for (int j = 0; j < 64; j++){
            float a1 = __shfl(hh1, j, 64);
            float a2 = __shfl(hh2, j, 64);
            u32 wp = w2p[j*64 + lane];
            acc = fmaf(a1, bf_lo(wp), acc);
            acc = fmaf(a2, bf_hi(wp), acc);
        }
        h_out[(size_t)node*64 + lane] = f2bf(fmaxf(acc, 0.f));
    }
}

// ---------------- head: out = concat(h, gf) @ head_w + head_b (fp32 out) ----------------
template<int IS32>
__global__ __launch_bounds__(256) void k_head(const u16* __restrict__ h,
                                              const void* __restrict__ gf,
                                              const int* __restrict__ ngp,
                                              const void* __restrict__ hw,
                                              const void* __restrict__ hb,
                                              const int* __restrict__ flg,
                                              float* __restrict__ out){
    if (flg[0] != IS32) return;
    int lane = threadIdx.x & 63;
    int wid  = (blockIdx.x*256 + threadIdx.x) >> 6;
    int nw   = (gridDim.x*256) >> 6;
    float wc  = ldx<IS32>(hw, lane);
    float w64 = ldx<IS32>(hw, 64), w65 = ldx<IS32>(hw, 65);
    float bias = ldx<IS32>(hb, 0);
    int ng  = ngp[0];
    if (ng <= 0) ng = 1;
    int npg = NN / ng;
    if (npg <= 0) npg = 1;
    for (int node = wid; node < NN; node += nw){
        float v = bf16f(h[(size_t)node*64 + lane]) * wc;
        #pragma unroll
        for (int off = 32; off > 0; off >>= 1) v += __shfl_xor(v, off, 64);
        if (lane == 0){
            int gidx = node / npg, r = node - gidx*npg;
            float g0 = ldx<IS32>(gf, (gidx*2 + 0)*npg + r);
            float g1 = ldx<IS32>(gf, (gidx*2 + 1)*npg + r);
            out[node] = v + g0*w64 + g1*w65 + bias;
        }
    }
}

// ---------------- launch ----------------
extern "C" void kernel_launch(void* const* d_in, const int* in_sizes, int n_in,
                              void* d_out, int out_size, void* d_ws, size_t ws_size,
                              hipStream_t stream){
    const void* x    = d_in[0];
    const int*  ei   = (const int*)d_in[1];          // [2, NE]: row0=src, row1=dst
    const void* ea   = d_in[2];
    const int*  ngp  = (const int*)d_in[3];
    const void* gf   = d_in[4];
    const void* srcw = d_in[5];
    const void* srcb = d_in[6];
    const void* L[16];
    for (int i = 0; i < 16; i++) L[i] = d_in[7 + i];
    const void* headw = d_in[23];
    const void* headb = d_in[24];

    char* ws = (char*)d_ws;
    size_t off = 0;
    auto alloc = [&](size_t bytes) -> void* {
        void* p = ws + off;
        off += (bytes + 255) & ~size_t(255);
        return p;
    };
    u16* hA      = (u16*) alloc((size_t)NN*64*2);    // 12.8 MB
    u16* hB      = (u16*) alloc((size_t)NN*64*2);    // 12.8 MB
    int* row_ptr = (int*) alloc((size_t)(NN+1)*4);
    int* cnt     = (int*) alloc((size_t)2*NN*4);     // deg | fill
    int* deg  = cnt;
    int* fill = cnt + NN;
    int* csum    = (int*) alloc((size_t)NCHUNK*4);
    int* coff    = (int*) alloc((size_t)NCHUNK*4);
    int* flg     = (int*) alloc(256);
    size_t common = off;
    // sorted mode needs: src_sorted 6.4 MB + ea_sorted 51.2 MB on top of common (~27 MB)
    bool sorted = (ws_size >= common + (size_t)NE*4 + (size_t)NE*32 + (1<<20));
    int*  src_sorted = nullptr;  u16* ea_sorted = nullptr;  int2* pair_sorted = nullptr;
    if (sorted){
        src_sorted = (int*)alloc((size_t)NE*4);
        ea_sorted  = (u16*)alloc((size_t)NE*32);
    } else {
        pair_sorted = (int2*)alloc((size_t)NE*8);
    }

    hipMemsetAsync(cnt, 0, (size_t)2*NN*4, stream);

    const int* e_src = ei;
    const int* e_dst = ei + NE;

    k_sniff      <<<1, 256, 0, stream>>>((const u32*)x, flg);
    k_deg        <<<1024, 256, 0, stream>>>(e_dst, deg);
    k_csum       <<<NCHUNK, 256, 0, stream>>>(deg, csum);
    k_scan_chunks<<<1, 512, 0, stream>>>(csum, coff);
    k_rowptr     <<<NCHUNK, 256, 0, stream>>>(deg, coff, row_ptr);
    if (sorted){
        k_scatter_s<1><<<1024, 256, 0, stream>>>(e_src, e_dst, ea, row_ptr, fill, flg, src_sorted, ea_sorted);
        k_scatter_s<0><<<1024, 256, 0, stream>>>(e_src, e_dst, ea, row_ptr, fill, flg, src_sorted, ea_sorted);
    } else {
        k_scatter_f<<<1024, 256, 0, stream>>>(e_src, e_dst, row_ptr, fill, pair_sorted);
    }

    k_proj<1><<<512, 256, 0, stream>>>(x, srcw, srcb, flg, hA);
    k_proj<0><<<512, 256, 0, stream>>>(x, srcw, srcb, flg, hA);

    const uint4* eas4 = (const uint4*)ea_sorted;
    for (int layer = 0; layer < 2; layer++){
        const void* const* W = layer ? &L[8] : &L[0];
        const u16* hin  = layer ? hB : hA;
        u16*       hout = layer ? hA : hB;
        if (sorted){
            k_layer<1,1><<<1280, 256, 0, stream>>>(hin, row_ptr, src_sorted, eas4, pair_sorted, ea,
                W[0], W[1], W[2], W[3], W[4], W[5], W[6], W[7], flg, hout);
            k_layer<0,1><<<1280, 256, 0, stream>>>(hin, row_ptr, src_sorted, eas4, pair_sorted, ea,
                W[0], W[1], W[2], W[3], W[4], W[5], W[6], W[7], flg, hout);
        } else {
            k_layer<1,0><<<1280, 256, 0, stream>>>(hin, row_ptr, src_sorted, eas4, pair_sorted, ea,
                W[0], W[1], W[2], W[3], W[4], W[5], W[6], W[7], flg, hout);
            k_layer<0,0><<<1280, 256, 0, stream>>>(hin, row_ptr, src_sorted, eas4, pair_sorted, ea,
                W[0], W[1], W[2], W[3], W[4], W[5], W[6], W[7], flg, hout);
        }
    }

    k_head<1><<<512, 256, 0, stream>>>(hA, gf, ngp, headw, headb, flg, (float*)d_out);
    k_head<0><<<512, 256, 0, stream>>>(hA, gf, ngp, headw, headb, flg, (float*)d_out);
}

// Round 8
// 5797.335 us; speedup vs baseline: 1.3166x; 1.3166x over previous
//
#include <hip/hip_runtime.h>
#include <hip/hip_bf16.h>
#include <hip/hip_fp16.h>

#define NN 100000
#define NE 1600000
#define NCHUNK 391   // ceil(100000/256)

typedef unsigned short u16;
typedef unsigned int   u32;

__device__ __forceinline__ float bfu(u32 v){ union{u32 i; float f;} w; w.i = v<<16; return w.f; }
__device__ __forceinline__ float bf_lo(u32 u){ return bfu(u & 0xffffu); }
__device__ __forceinline__ float bf_hi(u32 u){ return bfu(u >> 16); }
__device__ __forceinline__ float bf16f(u16 u){ return bfu((u32)u); }
__device__ __forceinline__ u16 f2bf(float f){
    union{float f; u32 i;} w; w.f = f;
    u32 r = (w.i + 0x7fffu + ((w.i >> 16) & 1u)) >> 16;   // RNE
    return (u16)r;
}

template<int IS32>
__device__ __forceinline__ float ldx(const void* p, int i){
    if (IS32) return ((const float*)p)[i];
    else      return bf16f(((const u16*)p)[i]);
}

// ---------------- dtype sniff: fp32 (1) vs bf16 (0) ----------------
__global__ void k_sniff(const u32* __restrict__ x, int* __restrict__ flag){
    __shared__ int cnt[256];
    int t = threadIdx.x;
    int bad = 0;
    for (int i = t; i < 512; i += 256){
        u32 w = x[i];
        u32 lo = w & 0xffffu;
        u32 e = (lo >> 7) & 0xffu;
        bool sane = (lo == 0u) || (lo == 0x8000u) || (e >= 85u && e <= 133u);
        if (!sane) bad++;
    }
    cnt[t] = bad; __syncthreads();
    for (int s = 128; s > 0; s >>= 1){
        if (t < s) cnt[t] += cnt[t+s];
        __syncthreads();
    }
    if (t == 0) flag[0] = (cnt[0] > 100) ? 1 : 0;
}

// ---------------- CSR build ----------------

__global__ void k_deg(const int* __restrict__ dst, int* __restrict__ deg){
    int stride = gridDim.x * blockDim.x;
    for (int i = blockIdx.x*blockDim.x + threadIdx.x; i < NE; i += stride){
        int d = dst[i];
        if ((unsigned)d < (unsigned)NN) atomicAdd(&deg[d], 1);
    }
}

__global__ void k_csum(const int* __restrict__ deg, int* __restrict__ csum){
    __shared__ int sdata[256];
    int t = threadIdx.x;
    int idx = blockIdx.x*256 + t;
    sdata[t] = (idx < NN) ? deg[idx] : 0;
    __syncthreads();
    for (int s = 128; s > 0; s >>= 1){
        if (t < s) sdata[t] += sdata[t+s];
        __syncthreads();
    }
    if (t == 0) csum[blockIdx.x] = sdata[0];
}

__global__ void k_scan_chunks(const int* __restrict__ csum, int* __restrict__ coff){
    __shared__ int s[512];
    int t = threadIdx.x;
    int v = (t < NCHUNK) ? csum[t] : 0;
    s[t] = v; __syncthreads();
    int x = v;
    for (int off = 1; off < 512; off <<= 1){
        int y = (t >= off) ? s[t-off] : 0;
        __syncthreads();
        x += y; s[t] = x;
        __syncthreads();
    }
    if (t < NCHUNK) coff[t] = x - v;   // exclusive
}

__global__ void k_rowptr(const int* __restrict__ deg, const int* __restrict__ coff,
                         int* __restrict__ row_ptr){
    __shared__ int s[256];
    int t = threadIdx.x, b = blockIdx.x;
    int idx = b*256 + t;
    int v = (idx < NN) ? deg[idx] : 0;
    s[t] = v; __syncthreads();
    int x = v;
    for (int off = 1; off < 256; off <<= 1){
        int y = (t >= off) ? s[t-off] : 0;
        __syncthreads();
        x += y; s[t] = x;
        __syncthreads();
    }
    if (idx < NN)       row_ptr[idx] = coff[b] + x - v;   // exclusive
    if (idx == NN - 1)  row_ptr[NN]  = coff[b] + x;       // total = NE
}

__global__ void k_scatter(const int* __restrict__ src, const int* __restrict__ dst,
                          const int* __restrict__ row_ptr, int* __restrict__ fill,
                          int2* __restrict__ pair_sorted){
    int stride = gridDim.x * blockDim.x;
    for (int i = blockIdx.x*blockDim.x + threadIdx.x; i < NE; i += stride){
        int d = dst[i];
        if ((unsigned)d >= (unsigned)NN) continue;
        int p = row_ptr[d] + atomicAdd(&fill[d], 1);
        if ((unsigned)p < (unsigned)NE){
            int s = src[i];
            if ((unsigned)s >= (unsigned)NN) s = 0;
            pair_sorted[p] = make_int2(s, i);
        }
    }
}

// ---------------- input projection: h = x @ src_w + src_b (bf16 out) ----------------
template<int IS32>
__global__ __launch_bounds__(256) void k_proj(const void* __restrict__ x,
                                              const void* __restrict__ w,
                                              const void* __restrict__ b,
                                              const int* __restrict__ flg,
                                              u16* __restrict__ h){
    if (flg[0] != IS32) return;
    int lane = threadIdx.x & 63;
    int wid  = (blockIdx.x*256 + threadIdx.x) >> 6;
    int nw   = (gridDim.x*256) >> 6;
    float wr[32];
    #pragma unroll
    for (int k = 0; k < 32; k++) wr[k] = ldx<IS32>(w, k*64 + lane);
    float bias = ldx<IS32>(b, lane);
    for (int node = wid; node < NN; node += nw){
        float acc = bias;
        #pragma unroll
        for (int k = 0; k < 32; k++) acc = fmaf(ldx<IS32>(x, node*32 + k), wr[k], acc);
        h[(size_t)node*64 + lane] = f2bf(acc);
    }
}

// ---------------- Phase A: per-edge message v -> fp16 buffer (CSR order) ----------------
template<int IS32>
__global__ __launch_bounds__(256) void k_msg(
    const int2* __restrict__ pair_sorted,
    const void* __restrict__ ea,
    const void* __restrict__ ew, const void* __restrict__ eb,
    const u16*  __restrict__ h_in,
    const int*  __restrict__ flg,
    __half* __restrict__ vbuf)
{
    if (flg[0] != IS32) return;
    int lane = threadIdx.x & 63;
    int wv   = (blockIdx.x*256 + threadIdx.x) >> 6;
    int nwv  = (gridDim.x*256) >> 6;

    float ewr[16];
    #pragma unroll
    for (int k = 0; k < 16; k++) ewr[k] = ldx<IS32>(ew, k*64 + lane);
    float ebr = ldx<IS32>(eb, lane);

    int per = (NE + nwv - 1) / nwv;
    int p0 = wv * per;
    int p1 = p0 + per; if (p1 > NE) p1 = NE;

    for (int p = p0; p < p1; ++p){
        int2 pe = pair_sorted[p];
        int s = pe.x;
        if ((unsigned)s >= (unsigned)NN) s = 0;
        unsigned eid = (unsigned)pe.y;
        if (eid >= (unsigned)NE) eid = 0;
        float e = ebr;
        if (IS32){
            const float4* er = (const float4*)ea + (size_t)eid*4;
            float4 u0 = er[0], u1 = er[1], u2 = er[2], u3 = er[3];
            e = fmaf(u0.x, ewr[0],  e); e = fmaf(u0.y, ewr[1],  e);
            e = fmaf(u0.z, ewr[2],  e); e = fmaf(u0.w, ewr[3],  e);
            e = fmaf(u1.x, ewr[4],  e); e = fmaf(u1.y, ewr[5],  e);
            e = fmaf(u1.z, ewr[6],  e); e = fmaf(u1.w, ewr[7],  e);
            e = fmaf(u2.x, ewr[8],  e); e = fmaf(u2.y, ewr[9],  e);
            e = fmaf(u2.z, ewr[10], e); e = fmaf(u2.w, ewr[11], e);
            e = fmaf(u3.x, ewr[12], e); e = fmaf(u3.y, ewr[13], e);
            e = fmaf(u3.z, ewr[14], e); e = fmaf(u3.w, ewr[15], e);
        } else {
            const uint4* er = (const uint4*)ea + (size_t)eid*2;
            uint4 a0 = er[0], a1 = er[1];
            e = fmaf(bf_lo(a0.x), ewr[0],  e); e = fmaf(bf_hi(a0.x), ewr[1],  e);
            e = fmaf(bf_lo(a0.y), ewr[2],  e); e = fmaf(bf_hi(a0.y), ewr[3],  e);
            e = fmaf(bf_lo(a0.z), ewr[4],  e); e = fmaf(bf_hi(a0.z), ewr[5],  e);
            e = fmaf(bf_lo(a0.w), ewr[6],  e); e = fmaf(bf_hi(a0.w), ewr[7],  e);
            e = fmaf(bf_lo(a1.x), ewr[8],  e); e = fmaf(bf_hi(a1.x), ewr[9],  e);
            e = fmaf(bf_lo(a1.y), ewr[10], e); e = fmaf(bf_hi(a1.y), ewr[11], e);
            e = fmaf(bf_lo(a1.z), ewr[12], e); e = fmaf(bf_hi(a1.z), ewr[13], e);
            e = fmaf(bf_lo(a1.w), ewr[14], e); e = fmaf(bf_hi(a1.w), ewr[15], e);
        }
        float hs = bf16f(h_in[(size_t)s*64 + lane]);
        float v = fmaxf(hs + e, 0.f) + 1e-7f;
        vbuf[(size_t)p*64 + lane] = __float2half(v);
    }
}

// ---------------- Phase B: segment softmax-reduce + MLP ----------------
template<int IS32>
__global__ __launch_bounds__(256, 4) void k_red(
    const u16*   __restrict__ h_in,
    const int*   __restrict__ row_ptr,
    const __half* __restrict__ vbuf,
    const void* __restrict__ w1, const void* __restrict__ b1,
    const void* __restrict__ g,  const void* __restrict__ bb,
    const void* __restrict__ w2, const void* __restrict__ b2,
    const int* __restrict__ flg,
    u16* __restrict__ h_out)
{
    if (flg[0] != IS32) return;

    __shared__ u32 w1p[64*64];   // lo=w1[k][c], hi=w1[k][c+64]
    __shared__ u32 w2p[64*64];   // lo=w2[j][c], hi=w2[j+64][c]

    int t = threadIdx.x;
    for (int i = t; i < 64*64; i += 256){
        int k = i >> 6, c = i & 63;
        u32 lo, hi;
        if (IS32){
            lo = f2bf(((const float*)w1)[k*128 + c]);
            hi = f2bf(((const float*)w1)[k*128 + c + 64]);
        } else {
            lo = ((const u16*)w1)[k*128 + c];
            hi = ((const u16*)w1)[k*128 + c + 64];
        }
        w1p[i] = lo | (hi << 16);
        if (IS32){
            lo = f2bf(((const float*)w2)[k*64 + c]);
            hi = f2bf(((const float*)w2)[(k+64)*64 + c]);
        } else {
            lo = ((const u16*)w2)[k*64 + c];
            hi = ((const u16*)w2)[(k+64)*64 + c];
        }
        w2p[i] = lo | (hi << 16);
    }
    __syncthreads();

    int lane = t & 63;
    int wid  = (blockIdx.x*256 + t) >> 6;
    int nw   = (gridDim.x*256) >> 6;

    const float BNS = 0.9999950000374997f;   // 1/sqrt(1+1e-5)
    float b1a = ldx<IS32>(b1, lane), b1b = ldx<IS32>(b1, lane+64);
    float ga  = ldx<IS32>(g, lane)*BNS,  gb  = ldx<IS32>(g, lane+64)*BNS;
    float bba = ldx<IS32>(bb, lane),     bbb = ldx<IS32>(bb, lane+64);
    float b2r = ldx<IS32>(b2, lane);

    for (int node = wid; node < NN; node += nw){
        int p0 = row_ptr[node], p1 = row_ptr[node+1];
        float swA = 0.f, swB = 0.f, smA = 0.f, smB = 0.f;
        int p = p0;
        for (; p + 2 <= p1; p += 2){
            float v0 = __half2float(vbuf[(size_t)p*64 + lane]);
            float v1 = __half2float(vbuf[(size_t)(p+1)*64 + lane]);
            float x0 = __expf(v0), x1 = __expf(v1);
            swA += x0; smA = fmaf(x0, v0, smA);
            swB += x1; smB = fmaf(x1, v1, smB);
        }
        for (; p < p1; ++p){
            float v0 = __half2float(vbuf[(size_t)p*64 + lane]);
            float x0 = __expf(v0);
            swA += x0; smA = fmaf(x0, v0, smA);
        }
        float sw = swA + swB, swm = smA + smB;
        float agg = (sw > 0.f) ? (swm / sw) : 0.f;
        float out = agg + bf16f(h_in[(size_t)node*64 + lane]);

        float acc1 = b1a, acc2 = b1b;
        #pragma unroll
        for (int k = 0; k < 64; k++){
            float ok = __shfl(out, k, 64);
            u32 wp = w1p[k*64 + lane];
            acc1 = fmaf(ok, bf_lo(wp), acc1);
            acc2 = fmaf(ok, bf_hi(wp), acc2);
        }
        float hh1 = fmaxf(fmaf(acc1, ga, bba), 0.f);
        float hh2 = fmaxf(fmaf(acc2, gb, bbb), 0.f);
        float acc = b2r;
        #pragma unroll
        for (int j = 0; j < 64; j++){
            float a1 = __shfl(hh1, j, 64);
            float a2 = __shfl(hh2, j, 64);
            u32 wp = w2p[j*64 + lane];
            acc = fmaf(a1, bf_lo(wp), acc);
            acc = fmaf(a2, bf_hi(wp), acc);
        }
        h_out[(size_t)node*64 + lane] = f2bf(fmaxf(acc, 0.f));
    }
}

// ---------------- fallback: exact R6 fused layer (proven 2.47 ms/layer) ----------------
template<int IS32>
__global__ __launch_bounds__(256, 3) void k_layer_fb(
    const u16*   __restrict__ h_in,
    const int*   __restrict__ row_ptr,
    const int2*  __restrict__ pair_sorted,
    const void*  __restrict__ ea,
    const void* __restrict__ ew, const void* __restrict__ eb,
    const void* __restrict__ w1, const void* __restrict__ b1,
    const void* __restrict__ g,  const void* __restrict__ bb,
    const void* __restrict__ w2, const void* __restrict__ b2,
    const int* __restrict__ flg,
    u16* __restrict__ h_out)
{
    if (flg[0] != IS32) return;

    __shared__ u32   w1p[64*64];
    __shared__ float w2s[128*64];

    int t = threadIdx.x;
    for (int i = t; i < 64*64; i += 256){
        int k = i >> 6, c = i & 63;
        u32 lo, hi;
        if (IS32){
            lo = f2bf(((const float*)w1)[k*128 + c]);
            hi = f2bf(((const float*)w1)[k*128 + c + 64]);
        } else {
            lo = ((const u16*)w1)[k*128 + c];
            hi = ((const u16*)w1)[k*128 + c + 64];
        }
        w1p[i] = lo | (hi << 16);
    }
    for (int i = t; i < 128*64; i += 256) w2s[i] = ldx<IS32>(w2, i);
    __syncthreads();

    int lane = t & 63;
    int wid  = (blockIdx.x*256 + t) >> 6;
    int nw   = (gridDim.x*256) >> 6;

    float ewr[16];
    #pragma unroll
    for (int k = 0; k < 16; k++) ewr[k] = ldx<IS32>(ew, k*64 + lane);
    float ebr = ldx<IS32>(eb, lane);
    const float BNS = 0.9999950000374997f;
    float b1a = ldx<IS32>(b1, lane), b1b = ldx<IS32>(b1, lane+64);
    float ga  = ldx<IS32>(g, lane)*BNS,  gb  = ldx<IS32>(g, lane+64)*BNS;
    float bba = ldx<IS32>(bb, lane),     bbb = ldx<IS32>(bb, lane+64);
    float b2r = ldx<IS32>(b2, lane);

    for (int node = wid; node < NN; node += nw){
        int p0 = row_ptr[node], p1 = row_ptr[node+1];
        if (p0 < 0) p0 = 0;
        if (p1 > NE) p1 = NE;
        float m = -1e30f, sw = 0.f, swm = 0.f;
        for (int p = p0; p < p1; ++p){
            int2 pe = pair_sorted[p];
            int s = pe.x;
            if ((unsigned)s >= (unsigned)NN) s = 0;
            unsigned eid = (unsigned)pe.y;
            if (eid >= (unsigned)NE) eid = 0;
            float av[16];
            if (IS32){
                const float4* er = (const float4*)ea + (size_t)eid*4;
                #pragma unroll
                for (int q = 0; q < 4; q++){
                    float4 u = er[q];
                    av[q*4+0]=u.x; av[q*4+1]=u.y; av[q*4+2]=u.z; av[q*4+3]=u.w;
                }
            } else {
                const uint4* er = (const uint4*)ea + (size_t)eid*2;
                #pragma unroll
                for (int q = 0; q < 2; q++){
                    uint4 u = er[q];
                    av[q*8+0]=bf_lo(u.x); av[q*8+1]=bf_hi(u.x);
                    av[q*8+2]=bf_lo(u.y); av[q*8+3]=bf_hi(u.y);
                    av[q*8+4]=bf_lo(u.z); av[q*8+5]=bf_hi(u.z);
                    av[q*8+6]=bf_lo(u.w); av[q*8+7]=bf_hi(u.w);
                }
            }
            float hs = bf16f(h_in[(size_t)s*64 + lane]);
            float e = ebr;
            #pragma unroll
            for (int k = 0; k < 16; k++) e = fmaf(av[k], ewr[k], e);
            float v = fmaxf(hs + e, 0.f) + 1e-7f;
            float nm = fmaxf(m, v);
            float al = __expf(m - nm);
            float pw = __expf(v - nm);
            sw  = sw*al + pw;
            swm = swm*al + pw*v;
            m = nm;
        }
        float agg = (sw > 0.f) ? (swm / sw) : 0.f;
        float out = agg + bf16f(h_in[(size_t)node*64 + lane]);

        float acc1 = b1a, acc2 = b1b;
        #pragma unroll
        for (int k = 0; k < 64; k++){
            float ok = __shfl(out, k, 64);
            u32 wp = w1p[k*64 + lane];
            acc1 = fmaf(ok, bf_lo(wp), acc1);
            acc2 = fmaf(ok, bf_hi(wp), acc2);
        }
        float hh1 = fmaxf(fmaf(acc1, ga, bba), 0.f);
        float hh2 = fmaxf(fmaf(acc2, gb, bbb), 0.f);
        float acc = b2r;
        #pragma unroll
        for (int j = 0; j < 64; j++){
            float a1 = __shfl(hh1, j, 64);
            float a2 = __shfl(hh2, j, 64);
            acc = fmaf(a1, w2s[j*64 + lane], acc);
            acc = fmaf(a2, w2s[(j+64)*64 + lane], acc);
        }
        h_out[(size_t)node*64 + lane] = f2bf(fmaxf(acc, 0.f));
    }
}

// ---------------- head: out = concat(h, gf) @ head_w + head_b (fp32 out) ----------------
template<int IS32>
__global__ __launch_bounds__(256) void k_head(const u16* __restrict__ h,
                                              const void* __restrict__ gf,
                                              const int* __restrict__ ngp,
                                              const void* __restrict__ hw,
                                              const void* __restrict__ hb,
                                              const int* __restrict__ flg,
                                              float* __restrict__ out){
    if (flg[0] != IS32) return;
    int lane = threadIdx.x & 63;
    int wid  = (blockIdx.x*256 + threadIdx.x) >> 6;
    int nw   = (gridDim.x*256) >> 6;
    float wc  = ldx<IS32>(hw, lane);
    float w64 = ldx<IS32>(hw, 64), w65 = ldx<IS32>(hw, 65);
    float bias = ldx<IS32>(hb, 0);
    int ng  = ngp[0];
    if (ng <= 0) ng = 1;
    int npg = NN / ng;
    if (npg <= 0) npg = 1;
    for (int node = wid; node < NN; node += nw){
        float v = bf16f(h[(size_t)node*64 + lane]) * wc;
        #pragma unroll
        for (int off = 32; off > 0; off >>= 1) v += __shfl_xor(v, off, 64);
        if (lane == 0){
            int gidx = node / npg, r = node - gidx*npg;
            float g0 = ldx<IS32>(gf, (gidx*2 + 0)*npg + r);
            float g1 = ldx<IS32>(gf, (gidx*2 + 1)*npg + r);
            out[node] = v + g0*w64 + g1*w65 + bias;
        }
    }
}

// ---------------- launch ----------------
extern "C" void kernel_launch(void* const* d_in, const int* in_sizes, int n_in,
                              void* d_out, int out_size, void* d_ws, size_t ws_size,
                              hipStream_t stream){
    const void* x    = d_in[0];
    const int*  ei   = (const int*)d_in[1];          // [2, NE]: row0=src, row1=dst
    const void* ea   = d_in[2];
    const int*  ngp  = (const int*)d_in[3];
    const void* gf   = d_in[4];
    const void* srcw = d_in[5];
    const void* srcb = d_in[6];
    const void* L[16];
    for (int i = 0; i < 16; i++) L[i] = d_in[7 + i];
    const void* headw = d_in[23];
    const void* headb = d_in[24];

    char* ws = (char*)d_ws;
    size_t off = 0;
    auto alloc = [&](size_t bytes) -> void* {
        void* p = ws + off;
        off += (bytes + 255) & ~size_t(255);
        return p;
    };
    u16* hA          = (u16*) alloc((size_t)NN*64*2);    // 12.8 MB
    u16* hB          = (u16*) alloc((size_t)NN*64*2);    // 12.8 MB
    int* row_ptr     = (int*) alloc((size_t)(NN+1)*4);
    int* cnt         = (int*) alloc((size_t)2*NN*4);     // deg | fill
    int* deg  = cnt;
    int* fill = cnt + NN;
    int* csum        = (int*) alloc((size_t)NCHUNK*4);
    int* coff        = (int*) alloc((size_t)NCHUNK*4);
    int* flg         = (int*) alloc(256);
    int2* pair_sorted= (int2*)alloc((size_t)NE*8);       // 12.8 MB
    size_t common = off;                                  // ~39.7 MB
    // two-phase mode needs vbuf: NE*64 fp16 = 204.8 MB
    bool twophase = (ws_size >= common + (size_t)NE*64*2 + (1<<20));
    __half* vbuf = nullptr;
    if (twophase) vbuf = (__half*)alloc((size_t)NE*64*2);

    hipMemsetAsync(cnt, 0, (size_t)2*NN*4, stream);

    const int* e_src = ei;
    const int* e_dst = ei + NE;

    k_sniff      <<<1, 256, 0, stream>>>((const u32*)x, flg);
    k_deg        <<<1024, 256, 0, stream>>>(e_dst, deg);
    k_csum       <<<NCHUNK, 256, 0, stream>>>(deg, csum);
    k_scan_chunks<<<1, 512, 0, stream>>>(csum, coff);
    k_rowptr     <<<NCHUNK, 256, 0, stream>>>(deg, coff, row_ptr);
    k_scatter    <<<1024, 256, 0, stream>>>(e_src, e_dst, row_ptr, fill, pair_sorted);

    k_proj<1><<<512, 256, 0, stream>>>(x, srcw, srcb, flg, hA);
    k_proj<0><<<512, 256, 0, stream>>>(x, srcw, srcb, flg, hA);

    for (int layer = 0; layer < 2; layer++){
        const void* const* W = layer ? &L[8] : &L[0];
        const u16* hin  = layer ? hB : hA;
        u16*       hout = layer ? hA : hB;
        if (twophase){
            k_msg<1><<<2048, 256, 0, stream>>>(pair_sorted, ea, W[0], W[1], hin, flg, vbuf);
            k_msg<0><<<2048, 256, 0, stream>>>(pair_sorted, ea, W[0], W[1], hin, flg, vbuf);
            k_red<1><<<1024, 256, 0, stream>>>(hin, row_ptr, vbuf,
                W[2], W[3], W[4], W[5], W[6], W[7], flg, hout);
            k_red<0><<<1024, 256, 0, stream>>>(hin, row_ptr, vbuf,
                W[2], W[3], W[4], W[5], W[6], W[7], flg, hout);
        } else {
            k_layer_fb<1><<<1024, 256, 0, stream>>>(hin, row_ptr, pair_sorted, ea,
                W[0], W[1], W[2], W[3], W[4], W[5], W[6], W[7], flg, hout);
            k_layer_fb<0><<<1024, 256, 0, stream>>>(hin, row_ptr, pair_sorted, ea,
                W[0], W[1], W[2], W[3], W[4], W[5], W[6], W[7], flg, hout);
        }
    }

    k_head<1><<<512, 256, 0, stream>>>(hA, gf, ngp, headw, headb, flg, (float*)d_out);
    k_head<0><<<512, 256, 0, stream>>>(hA, gf, ngp, headw, headb, flg, (float*)d_out);
}